// Round 9
// baseline (173.175 us; speedup 1.0000x reference)
//
#include <hip/hip_runtime.h>

#define F_IN 256
#define F_OUT 64
#define BSH 7             // bin width 128 nodes
#define BINW 128
#define NBINS_CAP 512     // LDS histogram capacity (N <= 65536)
#define BATCH 4096        // edges per bin-block (8 per thread at 512 thr)
#define CSTRIDE 16        // cursor padded to one 64B line per bin (R9)
#define MAXBIN_CAP 2560   // per-bin staging capacity (5 rounds x 512 threads)

typedef __attribute__((ext_vector_type(8))) short short8;
typedef __attribute__((ext_vector_type(4))) float f32x4;

// ---------------------------------------------------------------------------
// bf16 helpers. Hot-path pack via HW v_cvt_pk_bf16_f32 (RNE, 2 floats/instr).
// ---------------------------------------------------------------------------
__device__ inline float bf_lo(unsigned u) { return __uint_as_float(u << 16); }
__device__ inline float bf_hi(unsigned u) { return __uint_as_float(u & 0xFFFF0000u); }
__device__ inline unsigned cvt_pk_bf16(float lo, float hi) {
    unsigned r;
    asm("v_cvt_pk_bf16_f32 %0, %1, %2" : "=v"(r) : "v"(lo), "v"(hi));
    return r;
}
__device__ inline short8 pack_cvt(float4 a, float4 b) {
    union { unsigned u[4]; short8 s; } r;
    r.u[0] = cvt_pk_bf16(a.x, a.y);
    r.u[1] = cvt_pk_bf16(a.z, a.w);
    r.u[2] = cvt_pk_bf16(b.x, b.y);
    r.u[3] = cvt_pk_bf16(b.z, b.w);
    return r.s;
}

// ---------------------------------------------------------------------------
// K1 (fused, heterogeneous blocks, NO grid sync — the two halves are data-
// independent; R18): blocks [0,nbat) run the proven bin_count body (stage
// edges by dst>>BSH; ALSO feed global deg[dst] with no-return atomics — R5
// showed these pipeline fine; it was its scattered sub-line STORES that were
// poison). Blocks [nbat,..) run the proven MFMA gemm storing PLAIN h = x@W
// (bf16) — dinv moved to the gather, which breaks gemm's dependency on
// binning and lets the latency-bound bin blocks overlap the MFMA blocks in
// one dispatch (R8 budget: bin+gemm+gaps ~75-110us serialized).
// R16 rule: LDS atomics index __shared__ arrays directly.
// ---------------------------------------------------------------------------
__global__ __launch_bounds__(512, 4) void fused_bin_gemm(
    const float* __restrict__ x, const int* __restrict__ adj,
    const float* __restrict__ W, unsigned* __restrict__ staging,
    int* __restrict__ cursor, int* __restrict__ deg, unsigned* __restrict__ gu,
    int N, int E, int nbins, int maxBin, int nbat) {
    __shared__ union {
        struct { int cnt[NBINS_CAP]; int base[NBINS_CAP]; } p1;
        unsigned Wf[32 * 64 * 4];  // 32 KB: [kchunk][n][4 x u32(bf16x2)]
    } sh;
    const int tid = threadIdx.x;

    if ((int)blockIdx.x < nbat) {
        // ---- bin_count body (512 thr, 8 edges/thread) ----
        for (int i = tid; i < NBINS_CAP; i += 512) sh.p1.cnt[i] = 0;
        __syncthreads();
        const int e0 = blockIdx.x * BATCH + tid * 8;
        int S[8], D[8], sl[8];
        int nv = 0;
        if (e0 + 8 <= E && (E & 3) == 0) {
#pragma unroll
            for (int k = 0; k < 2; k++) {
                *(int4*)&S[k * 4] = *(const int4*)&adj[e0 + k * 4];
                *(int4*)&D[k * 4] = *(const int4*)&adj[E + e0 + k * 4];
            }
            nv = 8;
        } else if (e0 < E) {
            for (int k = 0; k < 8 && e0 + k < E; k++) {
                S[k] = adj[e0 + k];
                D[k] = adj[E + e0 + k];
                nv++;
            }
        }
#pragma unroll
        for (int j = 0; j < 8; j++) {
            if (j < nv) {
                sl[j] = atomicAdd(&sh.p1.cnt[D[j] >> BSH], 1);
                atomicAdd(&deg[D[j]], 1);  // no-return global atomic
            }
        }
        __syncthreads();
        for (int i = tid; i < nbins; i += 512) {
            int cv = sh.p1.cnt[i];
            sh.p1.base[i] = cv ? atomicAdd(&cursor[i * CSTRIDE], cv) : 0;
        }
        __syncthreads();
#pragma unroll
        for (int j = 0; j < 8; j++) {
            if (j < nv) {
                int b = D[j] >> BSH;
                int pos = sh.p1.base[b] + sl[j];
                if (pos < maxBin)
                    staging[(size_t)b * maxBin + pos] =
                        (unsigned)S[j] | ((unsigned)(D[j] & (BINW - 1)) << 16);
            }
        }
        return;
    }

    // ---- gemm body: h(bf16) = x @ W, 128 nodes/block, 8 waves ----
    const int b = blockIdx.x - nbat;
    for (int p = tid; p < (F_IN / 2) * F_OUT; p += 512) {
        int kp = p >> 6;
        int n = p & 63;
        int k = kp * 2;
        sh.Wf[((k >> 3) * 64 + n) * 4 + ((k & 7) >> 1)] =
            cvt_pk_bf16(W[k * F_OUT + n], W[(k + 1) * F_OUT + n]);
    }
    __syncthreads();

    const int wave = tid >> 6;
    const int lane = tid & 63;
    const int q = lane >> 4;
    const int c = lane & 15;
    const int n0 = b * 128 + wave * 16;
    const int r = min(n0 + c, N - 1);
    const float* p0 = x + (size_t)r * F_IN + q * 8;

    f32x4 acc[4] = {};
#pragma unroll
    for (int s = 0; s < 8; s++) {
        float4 a0 = *(const float4*)(p0 + s * 32);
        float4 a1 = *(const float4*)(p0 + s * 32 + 4);
        short8 ah = pack_cvt(a0, a1);
#pragma unroll
        for (int t = 0; t < 4; t++) {
            short8 bh = *(const short8*)&sh.Wf[((s * 4 + q) * 64 + t * 16 + c) * 4];
            acc[t] = __builtin_amdgcn_mfma_f32_16x16x32_bf16(ah, bh, acc[t], 0, 0, 0);
        }
    }

    // D layout: col = t*16 + c (feature), row = q*4 + rr (node). Pack col
    // pairs via shfl_xor(1), store bf16x2. No dinv here (moved to gather).
#pragma unroll
    for (int rr = 0; rr < 4; rr++) {
        int node = n0 + q * 4 + rr;
#pragma unroll
        for (int t = 0; t < 4; t++) {
            float v = acc[t][rr];
            float o = __shfl_xor(v, 1, 64);
            if (node < N && !(lane & 1)) {
                gu[(size_t)node * 32 + t * 8 + (c >> 1)] = cvt_pk_bf16(v, o);
            }
        }
    }
}

// ---------------------------------------------------------------------------
// K2: gather via bin-local CSR in LDS (proven R7 structure, full 128-node
// bins, 512 thr). New in R18: per-edge dinv[src] = rsqrtf(deg[src]+1)
// applied during accumulation (fmaf), since g now stores plain h. deg[s] is
// one uniform 4B load per 8-lane group (cache broadcast); dst's own deg
// comes free from the local CSR histogram. Numerics: bf16 rounding of h
// still dominates (dinv multiplies exact f32).
// ---------------------------------------------------------------------------
__global__ __launch_bounds__(512) void gather_bin(const unsigned* __restrict__ staging,
                                                  const int* __restrict__ cursor,
                                                  const int* __restrict__ deg,
                                                  const unsigned* __restrict__ g32,
                                                  const float* __restrict__ bias,
                                                  float* __restrict__ out,
                                                  int N, int maxBin) {
    __shared__ int cnt[BINW];
    __shared__ int off[BINW];
    __shared__ int wsum[2];
    __shared__ unsigned short binCsr[MAXBIN_CAP];
    const int b = blockIdx.x;
    const int tid = threadIdx.x;
    const int nb0 = b << BSH;

    if (tid < BINW) cnt[tid] = 0;
    __syncthreads();

    const int segCnt = min(cursor[b * CSTRIDE], maxBin);
    const unsigned* seg = staging + (size_t)b * maxBin;

    unsigned ev[5];
    int sl[5];
    int nv = 0;
#pragma unroll
    for (int r = 0; r < 5; r++) {
        int i = tid + r * 512;
        if (i < segCnt) {
            unsigned e = seg[i];
            ev[r] = e;
            sl[r] = atomicAdd(&cnt[e >> 16], 1);
            nv = r + 1;
        }
    }
    __syncthreads();

    int incl = 0, v = 0;
    if (tid < BINW) {  // 2-wave exclusive scan of cnt[128]
        v = cnt[tid];
        incl = v;
        const int lane = tid & 63;
        for (int d = 1; d < 64; d <<= 1) {
            int t = __shfl_up(incl, d, 64);
            if (lane >= d) incl += t;
        }
        if (lane == 63) wsum[tid >> 6] = incl;
    }
    __syncthreads();
    if (tid < BINW) off[tid] = incl - v + ((tid >= 64) ? wsum[0] : 0);
    __syncthreads();

#pragma unroll
    for (int r = 0; r < 5; r++) {
        if (r < nv) binCsr[off[ev[r] >> 16] + sl[r]] = (unsigned short)(ev[r] & 0xFFFFu);
    }
    __syncthreads();

    const int wv = tid >> 6;
    const int lane = tid & 63;
    const int grp = lane >> 3;
    const int h = lane & 7;
    const uint4* g4 = (const uint4*)g32;

    for (int t = 0; t < 16; t++) {
        const int node = wv * 16 + t;
        const int gn = nb0 + node;
        if (gn >= N) break;
        const int start = off[node];
        const int dg = cnt[node];

        float a0[8] = {}, a1[8] = {};
        int i = grp;
        for (; i + 8 < dg; i += 16) {
            int s0 = binCsr[start + i], s1 = binCsr[start + i + 8];
            float ds0 = rsqrtf((float)deg[s0] + 1.0f);
            float ds1 = rsqrtf((float)deg[s1] + 1.0f);
            uint4 u0 = g4[(size_t)s0 * 8 + h];
            uint4 u1 = g4[(size_t)s1 * 8 + h];
            a0[0] = fmaf(ds0, bf_lo(u0.x), a0[0]); a0[1] = fmaf(ds0, bf_hi(u0.x), a0[1]);
            a0[2] = fmaf(ds0, bf_lo(u0.y), a0[2]); a0[3] = fmaf(ds0, bf_hi(u0.y), a0[3]);
            a0[4] = fmaf(ds0, bf_lo(u0.z), a0[4]); a0[5] = fmaf(ds0, bf_hi(u0.z), a0[5]);
            a0[6] = fmaf(ds0, bf_lo(u0.w), a0[6]); a0[7] = fmaf(ds0, bf_hi(u0.w), a0[7]);
            a1[0] = fmaf(ds1, bf_lo(u1.x), a1[0]); a1[1] = fmaf(ds1, bf_hi(u1.x), a1[1]);
            a1[2] = fmaf(ds1, bf_lo(u1.y), a1[2]); a1[3] = fmaf(ds1, bf_hi(u1.y), a1[3]);
            a1[4] = fmaf(ds1, bf_lo(u1.z), a1[4]); a1[5] = fmaf(ds1, bf_hi(u1.z), a1[5]);
            a1[6] = fmaf(ds1, bf_lo(u1.w), a1[6]); a1[7] = fmaf(ds1, bf_hi(u1.w), a1[7]);
        }
        if (i < dg) {
            int s0 = binCsr[start + i];
            float ds0 = rsqrtf((float)deg[s0] + 1.0f);
            uint4 u0 = g4[(size_t)s0 * 8 + h];
            a0[0] = fmaf(ds0, bf_lo(u0.x), a0[0]); a0[1] = fmaf(ds0, bf_hi(u0.x), a0[1]);
            a0[2] = fmaf(ds0, bf_lo(u0.y), a0[2]); a0[3] = fmaf(ds0, bf_hi(u0.y), a0[3]);
            a0[4] = fmaf(ds0, bf_lo(u0.z), a0[4]); a0[5] = fmaf(ds0, bf_hi(u0.z), a0[5]);
            a0[6] = fmaf(ds0, bf_lo(u0.w), a0[6]); a0[7] = fmaf(ds0, bf_hi(u0.w), a0[7]);
        }
        float acc[8];
#pragma unroll
        for (int k = 0; k < 8; k++) acc[k] = a0[k] + a1[k];
#pragma unroll
        for (int m = 8; m < 64; m <<= 1) {
#pragma unroll
            for (int k = 0; k < 8; k++) acc[k] += __shfl_xor(acc[k], m, 64);
        }
        if (grp == 0) {
            uint4 us = g4[(size_t)gn * 8 + h];  // self loop (plain h row)
            float dv = rsqrtf((float)dg + 1.0f);
            float s0 = bf_lo(us.x), s1 = bf_hi(us.x), s2 = bf_lo(us.y), s3 = bf_hi(us.y);
            float s4 = bf_lo(us.z), s5 = bf_hi(us.z), s6 = bf_lo(us.w), s7 = bf_hi(us.w);
            float4 b0 = *(const float4*)&bias[h * 8];
            float4 b1 = *(const float4*)&bias[h * 8 + 4];
            // total = acc + dv*h_self; out = relu(dv*total + bias)
            float t0 = fmaf(dv, s0, acc[0]), t1 = fmaf(dv, s1, acc[1]);
            float t2 = fmaf(dv, s2, acc[2]), t3 = fmaf(dv, s3, acc[3]);
            float t4 = fmaf(dv, s4, acc[4]), t5 = fmaf(dv, s5, acc[5]);
            float t6 = fmaf(dv, s6, acc[6]), t7 = fmaf(dv, s7, acc[7]);
            float4 r0, r1;
            r0.x = fmaxf(fmaf(dv, t0, b0.x), 0.0f);
            r0.y = fmaxf(fmaf(dv, t1, b0.y), 0.0f);
            r0.z = fmaxf(fmaf(dv, t2, b0.z), 0.0f);
            r0.w = fmaxf(fmaf(dv, t3, b0.w), 0.0f);
            r1.x = fmaxf(fmaf(dv, t4, b1.x), 0.0f);
            r1.y = fmaxf(fmaf(dv, t5, b1.y), 0.0f);
            r1.z = fmaxf(fmaf(dv, t6, b1.z), 0.0f);
            r1.w = fmaxf(fmaf(dv, t7, b1.w), 0.0f);
            *(float4*)&out[(size_t)gn * F_OUT + h * 8] = r0;
            *(float4*)&out[(size_t)gn * F_OUT + h * 8 + 4] = r1;
        }
    }
}

extern "C" void kernel_launch(void* const* d_in, const int* in_sizes, int n_in,
                              void* d_out, int out_size, void* d_ws, size_t ws_size,
                              hipStream_t stream) {
    const float* x = (const float*)d_in[0];
    const int* adj = (const int*)d_in[1];
    const float* W = (const float*)d_in[2];
    const float* b = (const float*)d_in[3];
    float* out = (float*)d_out;

    const int N = in_sizes[0] / F_IN;  // 50000 (u16 packing assumes N <= 65536)
    const int E = in_sizes[1] / 2;     // 800000
    const int nbins = (N + BINW - 1) >> BSH;  // 391 (<= NBINS_CAP)
    const int maxBin = MAXBIN_CAP;            // 2560, ~11 sd above mean 2047
    const int nbat = (E + BATCH - 1) / BATCH; // 196 bin blocks
    const int ngemm = (N + 127) / 128;        // 391 gemm blocks

    // ws: [cursor(nbins*64B) | deg(N*4)] zeroed together | staging | g16
    char* ws = (char*)d_ws;
    size_t segCur = (((size_t)nbins * CSTRIDE * 4) + 255) & ~(size_t)255;
    size_t segDeg = (((size_t)N * 4) + 255) & ~(size_t)255;
    size_t segStg = (((size_t)nbins * maxBin * 4) + 255) & ~(size_t)255;
    int* cursor = (int*)ws;
    int* deg = (int*)(ws + segCur);
    unsigned* staging = (unsigned*)(ws + segCur + segDeg);
    unsigned* g16 = (unsigned*)(ws + segCur + segDeg + segStg);

    hipMemsetAsync(cursor, 0, segCur + segDeg, stream);  // cursors + deg

    fused_bin_gemm<<<nbat + ngemm, 512, 0, stream>>>(x, adj, W, staging, cursor,
                                                     deg, g16, N, E, nbins,
                                                     maxBin, nbat);
    gather_bin<<<nbins, 512, 0, stream>>>(staging, cursor, deg, g16, b, out, N, maxBin);
}

// Round 10
// 158.277 us; speedup vs baseline: 1.0941x; 1.0941x over previous
//
#include <hip/hip_runtime.h>

#define F_IN 256
#define F_OUT 64
#define BSH 7             // bin width 128 nodes
#define BINW 128
#define NBINS_CAP 512     // LDS histogram capacity (N <= 65536)
#define BATCH 4096        // edges per bin block (16 per thread at 256 thr)
#define CAP 64            // per-(block,bin) fixed staging slots (pow2).
                          // Poisson(mean 10.45) >= 64 ~ 1e-30: no drops.
#define SEG_CAP 2560      // per-bin dense segment cap (mean 2047, ~11 sd)

typedef __attribute__((ext_vector_type(8))) short short8;
typedef __attribute__((ext_vector_type(4))) float f32x4;

// ---------------------------------------------------------------------------
// bf16 helpers. Hot-path pack via HW v_cvt_pk_bf16_f32 (RNE, 2 floats/instr).
// ---------------------------------------------------------------------------
__device__ inline float bf_lo(unsigned u) { return __uint_as_float(u << 16); }
__device__ inline float bf_hi(unsigned u) { return __uint_as_float(u & 0xFFFF0000u); }
__device__ inline unsigned cvt_pk_bf16(float lo, float hi) {
    unsigned r;
    asm("v_cvt_pk_bf16_f32 %0, %1, %2" : "=v"(r) : "v"(lo), "v"(hi));
    return r;
}
__device__ inline short8 pack_cvt(float4 a, float4 b) {
    union { unsigned u[4]; short8 s; } r;
    r.u[0] = cvt_pk_bf16(a.x, a.y);
    r.u[1] = cvt_pk_bf16(a.z, a.w);
    r.u[2] = cvt_pk_bf16(b.x, b.y);
    r.u[3] = cvt_pk_bf16(b.z, b.w);
    return r.s;
}

// ---------------------------------------------------------------------------
// K1: deterministic binning (R19). Each block owns a FIXED chunk
// staging[bin][block][CAP] — slot index from an LDS counter only. NO global
// atomics (R9 lesson: cursor RMW chains at the coherence point were the
// binning stall), no memset dependency (hist row fully written per block).
// Single-writer per chunk satisfies the R15 sub-line-scatter rule. R16 rule:
// LDS atomics index the __shared__ array directly.
// ---------------------------------------------------------------------------
__global__ __launch_bounds__(256) void bin_stage(const int* __restrict__ adj,
                                                 unsigned* __restrict__ staging,
                                                 int* __restrict__ hist,
                                                 int E, int nbins, int nbat) {
    __shared__ int cnt[NBINS_CAP];
    const int tid = threadIdx.x;
    const int k = blockIdx.x;
    for (int i = tid; i < NBINS_CAP; i += 256) cnt[i] = 0;
    __syncthreads();

    const int e0 = k * BATCH + tid * 16;
    int S[16], D[16];
    int nv = 0;
    if (e0 + 16 <= E) {
#pragma unroll
        for (int kk = 0; kk < 4; kk++) {
            *(int4*)&S[kk * 4] = *(const int4*)&adj[e0 + kk * 4];
            *(int4*)&D[kk * 4] = *(const int4*)&adj[E + e0 + kk * 4];
        }
        nv = 16;
    } else if (e0 < E) {
        for (int kk = 0; kk < 16 && e0 + kk < E; kk++) {
            S[kk] = adj[e0 + kk];
            D[kk] = adj[E + e0 + kk];
            nv++;
        }
    }
#pragma unroll
    for (int j = 0; j < 16; j++) {
        if (j < nv) {
            int b = D[j] >> BSH;
            int slot = atomicAdd(&cnt[b], 1);
            if (slot < CAP)
                staging[((size_t)b * nbat + k) * CAP + slot] =
                    (unsigned)S[j] | ((unsigned)(D[j] & (BINW - 1)) << 16);
        }
    }
    __syncthreads();
    for (int i = tid; i < nbins; i += 256) hist[k * nbins + i] = min(cnt[i], CAP);
}

// ---------------------------------------------------------------------------
// K2: fused [bin deg-hist -> dinv] + [g(bf16) = dinv*(x @ W) via MFMA].
// Proven R7 body; deg now summed from the chunked staging (validity-guarded
// slot scan over hist column). dinv folded back into g (R9's per-edge dinv
// in the gather cost ~20us — reverted).
// ---------------------------------------------------------------------------
__global__ __launch_bounds__(512, 4) void gemm_mfma(const float* __restrict__ x,
                                                    const float* __restrict__ W,
                                                    const unsigned* __restrict__ staging,
                                                    const int* __restrict__ hist,
                                                    unsigned* __restrict__ gu,
                                                    int N, int nbins, int nbat) {
    __shared__ unsigned Wf[32 * 64 * 4];  // 32 KB: [kchunk][n][4 x u32(bf16x2)]
    __shared__ int histL[256];
    __shared__ int degL[BINW];
    __shared__ float dinvL[BINW];
    const int b = blockIdx.x;
    const int tid = threadIdx.x;

    if (tid < BINW) degL[tid] = 0;
    if (tid < 256) histL[tid] = (tid < nbat) ? hist[tid * nbins + b] : 0;
    for (int p = tid; p < (F_IN / 2) * F_OUT; p += 512) {
        int kp = p >> 6;
        int n = p & 63;
        int k = kp * 2;
        Wf[((k >> 3) * 64 + n) * 4 + ((k & 7) >> 1)] =
            cvt_pk_bf16(W[k * F_OUT + n], W[(k + 1) * F_OUT + n]);
    }
    __syncthreads();

    const int slots = nbat * CAP;
    for (int i = tid; i < slots; i += 512) {
        int k = i >> 6;  // CAP == 64
        int s = i & (CAP - 1);
        if (s < histL[k]) {
            unsigned e = staging[((size_t)b * nbat + k) * CAP + s];
            atomicAdd(&degL[e >> 16], 1);
        }
    }
    __syncthreads();
    if (tid < BINW) dinvL[tid] = rsqrtf((float)degL[tid] + 1.0f);
    __syncthreads();

    const int wave = tid >> 6;
    const int lane = tid & 63;
    const int q = lane >> 4;
    const int c = lane & 15;
    const int n0 = b * 128 + wave * 16;
    const int r = min(n0 + c, N - 1);
    const float* p0 = x + (size_t)r * F_IN + q * 8;

    f32x4 acc[4] = {};
#pragma unroll
    for (int s = 0; s < 8; s++) {
        float4 a0 = *(const float4*)(p0 + s * 32);
        float4 a1 = *(const float4*)(p0 + s * 32 + 4);
        short8 ah = pack_cvt(a0, a1);
#pragma unroll
        for (int t = 0; t < 4; t++) {
            short8 bh = *(const short8*)&Wf[((s * 4 + q) * 64 + t * 16 + c) * 4];
            acc[t] = __builtin_amdgcn_mfma_f32_16x16x32_bf16(ah, bh, acc[t], 0, 0, 0);
        }
    }

    // D layout: col = t*16 + c (feature), row = q*4 + rr (node). Pack col
    // pairs via shfl_xor(1), store bf16x2.
#pragma unroll
    for (int rr = 0; rr < 4; rr++) {
        int node = n0 + q * 4 + rr;
        float dv = dinvL[wave * 16 + q * 4 + rr];
#pragma unroll
        for (int t = 0; t < 4; t++) {
            float v = acc[t][rr] * dv;
            float o = __shfl_xor(v, 1, 64);
            if (node < N && !(lane & 1)) {
                gu[(size_t)node * 32 + t * 8 + (c >> 1)] = cvt_pk_bf16(v, o);
            }
        }
    }
}

// ---------------------------------------------------------------------------
// K3: gather (proven R7 body). New prologue: hist-column scan -> chunk
// offsets -> dense-copy the bin's chunked edges into LDS segD, then the
// R7 local-CSR build + register-accumulate gather run unchanged (g is
// dinv-prescaled; dst dinv from local deg hist).
// ---------------------------------------------------------------------------
__global__ __launch_bounds__(512) void gather_bin(const unsigned* __restrict__ staging,
                                                  const int* __restrict__ hist,
                                                  const unsigned* __restrict__ g32,
                                                  const float* __restrict__ bias,
                                                  float* __restrict__ out,
                                                  int N, int nbins, int nbat) {
    __shared__ int hh[256];
    __shared__ int coff[256];
    __shared__ int wsum4[4];
    __shared__ unsigned segD[SEG_CAP];   // 10 KB
    __shared__ int cnt[BINW];
    __shared__ int off[BINW];
    __shared__ int wsum[2];
    __shared__ int segCntSh;
    __shared__ unsigned short binCsr[SEG_CAP];  // 5 KB
    const int b = blockIdx.x;
    const int tid = threadIdx.x;
    const int nb0 = b << BSH;

    if (tid < 256) hh[tid] = (tid < nbat) ? hist[tid * nbins + b] : 0;
    if (tid < BINW) cnt[tid] = 0;
    __syncthreads();

    // 4-wave exclusive scan of hh[256] -> coff
    if (tid < 256) {
        int v = hh[tid];
        int incl = v;
        const int lane = tid & 63;
        for (int d = 1; d < 64; d <<= 1) {
            int t = __shfl_up(incl, d, 64);
            if (lane >= d) incl += t;
        }
        if (lane == 63) wsum4[tid >> 6] = incl;
        coff[tid] = incl - v;
    }
    __syncthreads();
    if (tid < 256) {
        int add = 0;
        for (int w = 0; w < (tid >> 6); w++) add += wsum4[w];
        coff[tid] += add;
        if (tid == 255) segCntSh = coff[255] + hh[255];
    }
    __syncthreads();
    const int segCnt = min(segCntSh, SEG_CAP);

    // dense-copy chunked staging into segD
    for (int i = tid; i < nbat * CAP; i += 512) {
        int k = i >> 6;  // CAP == 64
        int s = i & (CAP - 1);
        if (s < hh[k]) {
            int pos = coff[k] + s;
            if (pos < SEG_CAP)
                segD[pos] = staging[((size_t)b * nbat + k) * CAP + s];
        }
    }
    __syncthreads();

    // ---- R7 proven body: local CSR build ----
    unsigned ev[5];
    int sl[5];
    int nv = 0;
#pragma unroll
    for (int r = 0; r < 5; r++) {
        int i = tid + r * 512;
        if (i < segCnt) {
            unsigned e = segD[i];
            ev[r] = e;
            sl[r] = atomicAdd(&cnt[e >> 16], 1);
            nv = r + 1;
        }
    }
    __syncthreads();

    int incl = 0, v = 0;
    if (tid < BINW) {  // 2-wave exclusive scan of cnt[128]
        v = cnt[tid];
        incl = v;
        const int lane = tid & 63;
        for (int d = 1; d < 64; d <<= 1) {
            int t = __shfl_up(incl, d, 64);
            if (lane >= d) incl += t;
        }
        if (lane == 63) wsum[tid >> 6] = incl;
    }
    __syncthreads();
    if (tid < BINW) off[tid] = incl - v + ((tid >= 64) ? wsum[0] : 0);
    __syncthreads();

#pragma unroll
    for (int r = 0; r < 5; r++) {
        if (r < nv) binCsr[off[ev[r] >> 16] + sl[r]] = (unsigned short)(ev[r] & 0xFFFFu);
    }
    __syncthreads();

    // ---- R7 proven body: register-accumulate gather ----
    const int wv = tid >> 6;
    const int lane = tid & 63;
    const int grp = lane >> 3;
    const int h = lane & 7;
    const uint4* g4 = (const uint4*)g32;

    for (int t = 0; t < 16; t++) {
        const int node = wv * 16 + t;
        const int gn = nb0 + node;
        if (gn >= N) break;
        const int start = off[node];
        const int deg = cnt[node];

        float a0[8] = {}, a1[8] = {};
        int i = grp;
        for (; i + 8 < deg; i += 16) {
            int s0 = binCsr[start + i], s1 = binCsr[start + i + 8];
            uint4 u0 = g4[(size_t)s0 * 8 + h];
            uint4 u1 = g4[(size_t)s1 * 8 + h];
            a0[0] += bf_lo(u0.x); a0[1] += bf_hi(u0.x);
            a0[2] += bf_lo(u0.y); a0[3] += bf_hi(u0.y);
            a0[4] += bf_lo(u0.z); a0[5] += bf_hi(u0.z);
            a0[6] += bf_lo(u0.w); a0[7] += bf_hi(u0.w);
            a1[0] += bf_lo(u1.x); a1[1] += bf_hi(u1.x);
            a1[2] += bf_lo(u1.y); a1[3] += bf_hi(u1.y);
            a1[4] += bf_lo(u1.z); a1[5] += bf_hi(u1.z);
            a1[6] += bf_lo(u1.w); a1[7] += bf_hi(u1.w);
        }
        if (i < deg) {
            int s0 = binCsr[start + i];
            uint4 u0 = g4[(size_t)s0 * 8 + h];
            a0[0] += bf_lo(u0.x); a0[1] += bf_hi(u0.x);
            a0[2] += bf_lo(u0.y); a0[3] += bf_hi(u0.y);
            a0[4] += bf_lo(u0.z); a0[5] += bf_hi(u0.z);
            a0[6] += bf_lo(u0.w); a0[7] += bf_hi(u0.w);
        }
        float acc[8];
#pragma unroll
        for (int k = 0; k < 8; k++) acc[k] = a0[k] + a1[k];
#pragma unroll
        for (int m = 8; m < 64; m <<= 1) {
#pragma unroll
            for (int k = 0; k < 8; k++) acc[k] += __shfl_xor(acc[k], m, 64);
        }
        if (grp == 0) {
            uint4 us = g4[(size_t)gn * 8 + h];  // self loop (dinv-prescaled)
            float dv = rsqrtf((float)deg + 1.0f);
            float s0 = bf_lo(us.x), s1 = bf_hi(us.x), s2 = bf_lo(us.y), s3 = bf_hi(us.y);
            float s4 = bf_lo(us.z), s5 = bf_hi(us.z), s6 = bf_lo(us.w), s7 = bf_hi(us.w);
            float4 b0 = *(const float4*)&bias[h * 8];
            float4 b1 = *(const float4*)&bias[h * 8 + 4];
            float4 r0, r1;
            r0.x = fmaxf(fmaf(dv, acc[0] + s0, b0.x), 0.0f);
            r0.y = fmaxf(fmaf(dv, acc[1] + s1, b0.y), 0.0f);
            r0.z = fmaxf(fmaf(dv, acc[2] + s2, b0.z), 0.0f);
            r0.w = fmaxf(fmaf(dv, acc[3] + s3, b0.w), 0.0f);
            r1.x = fmaxf(fmaf(dv, acc[4] + s4, b1.x), 0.0f);
            r1.y = fmaxf(fmaf(dv, acc[5] + s5, b1.y), 0.0f);
            r1.z = fmaxf(fmaf(dv, acc[6] + s6, b1.z), 0.0f);
            r1.w = fmaxf(fmaf(dv, acc[7] + s7, b1.w), 0.0f);
            *(float4*)&out[(size_t)gn * F_OUT + h * 8] = r0;
            *(float4*)&out[(size_t)gn * F_OUT + h * 8 + 4] = r1;
        }
    }
}

extern "C" void kernel_launch(void* const* d_in, const int* in_sizes, int n_in,
                              void* d_out, int out_size, void* d_ws, size_t ws_size,
                              hipStream_t stream) {
    const float* x = (const float*)d_in[0];
    const int* adj = (const int*)d_in[1];
    const float* W = (const float*)d_in[2];
    const float* b = (const float*)d_in[3];
    float* out = (float*)d_out;

    const int N = in_sizes[0] / F_IN;  // 50000 (u16 packing assumes N <= 65536)
    const int E = in_sizes[1] / 2;     // 800000
    const int nbins = (N + BINW - 1) >> BSH;   // 391 (<= NBINS_CAP)
    const int nbat = (E + BATCH - 1) / BATCH;  // 196 (<= 256, histL cap)

    // ws: staging(nbins*nbat*CAP u32 ~19.6MB) | hist(nbat*nbins) | g16(N*32 u32)
    // No memset: hist rows are fully written by bin_stage; staging slots are
    // validity-guarded by hist.
    char* ws = (char*)d_ws;
    size_t segStg = (((size_t)nbins * nbat * CAP * 4) + 255) & ~(size_t)255;
    size_t segHist = (((size_t)nbat * nbins * 4) + 255) & ~(size_t)255;
    unsigned* staging = (unsigned*)ws;
    int* hist = (int*)(ws + segStg);
    unsigned* g16 = (unsigned*)(ws + segStg + segHist);

    bin_stage<<<nbat, 256, 0, stream>>>(adj, staging, hist, E, nbins, nbat);
    gemm_mfma<<<nbins, 512, 0, stream>>>(x, W, staging, hist, g16, N, nbins, nbat);
    gather_bin<<<nbins, 512, 0, stream>>>(staging, hist, g16, b, out, N, nbins, nbat);
}